// Round 2
// baseline (1141.169 us; speedup 1.0000x reference)
//
#include <hip/hip_runtime.h>
#include <math.h>

// Problem constants
#define BB 8
#define CC 256
#define HH 128
#define WW 128
#define CP_OFF 33554432          // floats; cp half of d_out

// ---- workspace layout (float offsets) ----
#define ZB_OFF   0               // 256 floats of zeros (OOB load target)
#define P1S_OFF  256             // [8][256][128] f32
#define P1M_OFF  262400          // [8][256][128] u32 (ordered-key max)
#define P2S_OFF  524544          // [8][128]
#define P2M_OFF  525568          // [8][128]
#define P3S_OFF  526592          // [8][128]
#define P3M_OFF  527616          // [8][128]
#define U2_OFF   528640          // [8][128][4]
#define U3_OFF   532736          // [8][128][4]
#define V1_OFF   536832          // [8][256][4]
#define SPEC_OFF 545024          // [8][256]
#define WS_ZERO_BYTES (528640 * 4)   // zero zbuf + all reduction partials

typedef __attribute__((ext_vector_type(8))) short bf16x8;
typedef __attribute__((ext_vector_type(4))) float f32x4;

// ---------------- helpers ----------------
static __device__ __forceinline__ unsigned short f2bf(float f) {
    unsigned u = __float_as_uint(f);
    unsigned r = u + 0x7FFFu + ((u >> 16) & 1u);   // RNE
    return (unsigned short)(r >> 16);
}
static __device__ __forceinline__ unsigned fkey(float f) {
    unsigned u = __float_as_uint(f);
    return (u & 0x80000000u) ? ~u : (u | 0x80000000u);
}
static __device__ __forceinline__ float fkeydec(unsigned k) {
    return __uint_as_float((k & 0x80000000u) ? (k & 0x7FFFFFFFu) : ~k);
}
// async 16B global -> LDS. HW semantics: LDS dest = wave-uniform base +
// lane*16 (we pass the uniform base); global src is per-lane.
static __device__ __forceinline__ void gl_lds16(const void* g, void* l) {
    typedef const __attribute__((address_space(1))) unsigned int* gas_t;
    typedef __attribute__((address_space(3))) unsigned int* las_t;
    gas_t gp = (gas_t)(uintptr_t)g;
    las_t lp = (las_t)(unsigned int)(uintptr_t)l;
    __builtin_amdgcn_global_load_lds(gp, lp, 16, 0, 0);
}

// ---------------------------------------------------------------------------
// P1: weights fp32 [co 256][ci 512][3][3] -> Wt bf16 [tap 9][co 256][ci 512]
// ---------------------------------------------------------------------------
__global__ __launch_bounds__(256) void wt_kernel(
    const float* __restrict__ cw, unsigned short* __restrict__ Wt)
{
    const int g = blockIdx.x * 256 + threadIdx.x;    // 0..131071 = co*512+ci
    const int co = g >> 9, ci = g & 511;
    const float* s = cw + (size_t)g * 9;
    #pragma unroll
    for (int t = 0; t < 9; t++)
        Wt[((size_t)t * 256 + co) * 512 + ci] = f2bf(s[t]);
}

// ---------------------------------------------------------------------------
// P2: X transpose: frm/oth fp32 [b][c][h][w] -> Xt bf16 [b][h][w][ci 512]
// ---------------------------------------------------------------------------
__global__ __launch_bounds__(256) void xt_kernel(
    const float* __restrict__ frm, const float* __restrict__ oth,
    unsigned short* __restrict__ Xt)
{
    const int w = threadIdx.x & 127, half = threadIdx.x >> 7;
    const int h = blockIdx.x, b = blockIdx.y;
    const float* src = half ? oth : frm;
    const size_t inbase = (((size_t)b * 256) << 14) + ((size_t)h << 7) + w;
    unsigned short* op = Xt + ((((size_t)(b * 128 + h) * 128) + w) << 9) + half * 256;
    #pragma unroll 2
    for (int c8 = 0; c8 < 32; c8++) {
        unsigned short u[8];
        #pragma unroll
        for (int j = 0; j < 8; j++)
            u[j] = f2bf(src[inbase + (((size_t)(c8 * 8 + j)) << 14)]);
        uint4 pk;
        pk.x = (unsigned)u[0] | ((unsigned)u[1] << 16);
        pk.y = (unsigned)u[2] | ((unsigned)u[3] << 16);
        pk.z = (unsigned)u[4] | ((unsigned)u[5] << 16);
        pk.w = (unsigned)u[6] | ((unsigned)u[7] << 16);
        *(uint4*)(op + c8 * 8) = pk;
    }
}

// ---------------------------------------------------------------------------
// K1: MFMA implicit-GEMM conv + bias + leaky + fused mode reductions.
// Tile: 128 co x 128 px (one h-row of one b). grid 2048 (XCD-swizzled),
// block 256 (4 waves in 2x2).
// T3+T4 counted-vmcnt pipeline: every wave issues exactly 9
// global_load_lds per chunk (6 A + 3 B, wave-uniform). Per chunk:
//   stage(q+1) ; s_waitcnt vmcnt(9)   <- waits chunk q's loads only
//   s_barrier  ; 48 MFMA ; s_barrier  <- no vmcnt(0) drain in the loop
// LDS rows padded (A stride 130 units, B stride 138) so the four l4
// groups of a ds_read_b128 start at banks {0,8,16,24} (was all bank 0).
// ---------------------------------------------------------------------------
__global__ __launch_bounds__(256, 2) void conv_mfma(
    const unsigned short* __restrict__ Wt,
    const unsigned short* __restrict__ Xt,
    const float* __restrict__ cb,
    const unsigned short* __restrict__ zb,
    float* __restrict__ p1s, unsigned* __restrict__ p1m,
    float* __restrict__ p2s, unsigned* __restrict__ p2m,
    float* __restrict__ p3s, unsigned* __restrict__ p3m)
{
    // A: 12 rows (kw*4+ku) x 130-unit padded stride, data 128 units (co)
    // B:  4 rows (ku)      x 138-unit padded stride, data 136 units (wi)
    __shared__ __align__(16) unsigned short lA[2][1560 * 8];   // 2 x 24960 B
    __shared__ __align__(16) unsigned short lB[2][552 * 8];    // 2 x  8832 B

    const int tid = threadIdx.x;
    // XCD-aware swizzle: XCD k owns batch k's panel, h-major, cohalf-adjacent
    const int swz = (blockIdx.x & 7) * 256 + (blockIdx.x >> 3);
    const int b = swz >> 8;
    const int h = (swz >> 1) & 127;
    const int cohalf = swz & 1;

    const int lane = tid & 63, wid = tid >> 6;
    const int wm = wid & 1, wn = wid >> 1;
    const int l15 = lane & 15, l4 = lane >> 4;

    // ---- staging precompute (hoisted out of the chunk loop) ----
    // A: wave-chunk ch = i*4+wid -> row r = ch>>1 (kw=r>>2, ku=r&3), half
    const unsigned short* baseA[6];
    int dstA[6];
    #pragma unroll
    for (int i = 0; i < 6; i++) {
        const int ch = i * 4 + wid;
        const int r = ch >> 1, half = ch & 1;
        const int kw = r >> 2, ku = r & 3;
        baseA[i] = Wt + (size_t)(cohalf * 128 + half * 64 + lane) * 512
                      + kw * 131072 + ku * 8;
        dstA[i] = (r * 130 + half * 64) * 8;
    }
    // B: wave wid stages row ku = wid; 3 instructions (2 full + 8-lane tail)
    const unsigned short* baseB[3];
    bool okB[3];
    int dstB[3];
    #pragma unroll
    for (int j = 0; j < 3; j++) {
        const int wi = j * 64 + lane;
        const int wg = wi - 1;
        okB[j] = (wg >= 0) && (wg < WW);
        baseB[j] = Xt + (size_t)b * 8388608
                      + (size_t)(okB[j] ? wg : 0) * 512 + wid * 8;
        dstB[j] = (wid * 138 + j * 64) * 8;
    }

    f32x4 acc[4][4];
    #pragma unroll
    for (int m = 0; m < 4; m++)
        #pragma unroll
        for (int n = 0; n < 4; n++)
            acc[m][n] = (f32x4){0.f, 0.f, 0.f, 0.f};

    // stage chunk q (kh = q>>4, ci0 = (q&15)*32) into buffer bufi.
    // Exactly 9 VMEM instructions per wave, every wave.
    auto stage = [&](int q, int bufi) {
        const int kh = q >> 4;
        const int ci0 = (q & 15) << 5;
        const int hr = h + kh - 1;
        const bool hv = (hr >= 0) && (hr < HH);
        const int aoff = kh * 393216 + ci0;
        const int boff = (hv ? hr : 0) * 65536 + ci0;
        #pragma unroll
        for (int i = 0; i < 6; i++)
            gl_lds16(baseA[i] + aoff, &lA[bufi][dstA[i]]);
        #pragma unroll
        for (int j = 0; j < 2; j++) {
            const unsigned short* s = (hv && okB[j]) ? (baseB[j] + boff) : zb;
            gl_lds16(s, &lB[bufi][dstB[j]]);
        }
        {   // tail: 8 active lanes in EVERY wave (uniform vmcnt count)
            const unsigned short* s = (hv && okB[2]) ? (baseB[2] + boff) : zb;
            if (lane < 8) gl_lds16(s, &lB[bufi][dstB[2]]);
        }
    };

    auto compute = [&](int cur) {
        const unsigned short* A  = lA[cur];
        const unsigned short* Bl = lB[cur];
        #pragma unroll
        for (int kw = 0; kw < 3; kw++) {
            bf16x8 af[4], bfr[4];
            #pragma unroll
            for (int m = 0; m < 4; m++) {
                const int unit = (kw * 4 + l4) * 130 + wm * 64 + m * 16 + l15;
                af[m] = *(const bf16x8*)&A[unit * 8];
            }
            #pragma unroll
            for (int n = 0; n < 4; n++) {
                const int unit = l4 * 138 + wn * 64 + n * 16 + l15 + kw;
                bfr[n] = *(const bf16x8*)&Bl[unit * 8];
            }
            #pragma unroll
            for (int m = 0; m < 4; m++)
                #pragma unroll
                for (int n = 0; n < 4; n++)
                    acc[m][n] = __builtin_amdgcn_mfma_f32_16x16x32_bf16(
                        af[m], bfr[n], acc[m][n], 0, 0, 0);
        }
    };

    // prologue
    stage(0, 0);

    #pragma unroll 1
    for (int q = 0; q < 47; q++) {
        const int cur = q & 1;
        stage(q + 1, cur ^ 1);                         // prefetch next chunk
        // wait for chunk q's 9 loads (the 9 newest = q+1's stay in flight)
        asm volatile("s_waitcnt vmcnt(9)" ::: "memory");
        __builtin_amdgcn_s_barrier();                  // publish chunk q LDS
        __builtin_amdgcn_sched_barrier(0);
        __builtin_amdgcn_s_setprio(1);
        compute(cur);
        __builtin_amdgcn_s_setprio(0);
        __builtin_amdgcn_sched_barrier(0);
        __builtin_amdgcn_s_barrier();                  // gate buffer overwrite
    }
    // final chunk (47): nothing left in flight behind it
    asm volatile("s_waitcnt vmcnt(0)" ::: "memory");
    __builtin_amdgcn_s_barrier();
    __builtin_amdgcn_sched_barrier(0);
    __builtin_amdgcn_s_setprio(1);
    compute(1);
    __builtin_amdgcn_s_setprio(0);

    // ---- epilogue: bias + LeakyReLU, then fused mode reductions ----
    // D layout: co = cob + m*16 + l4*4 + r ; px(w) = wn*64 + n*16 + l15
    const int cob = cohalf * 128 + wm * 64;
    float t1s[4][4], t1m[4][4], s2[4], x2[4];
    #pragma unroll
    for (int n = 0; n < 4; n++) { s2[n] = 0.f; x2[n] = -INFINITY; }

    #pragma unroll
    for (int m = 0; m < 4; m++) {
        const float4 bb4 = *(const float4*)&cb[cob + m * 16 + l4 * 4];
        float bbv[4] = { bb4.x, bb4.y, bb4.z, bb4.w };
        #pragma unroll
        for (int r = 0; r < 4; r++) { t1s[m][r] = 0.f; t1m[m][r] = -INFINITY; }
        #pragma unroll
        for (int n = 0; n < 4; n++) {
            #pragma unroll
            for (int r = 0; r < 4; r++) {
                float v = acc[m][n][r] + bbv[r];
                v = (v >= 0.f) ? v : 0.01f * v;
                t1s[m][r] += v;
                t1m[m][r] = fmaxf(t1m[m][r], v);
                s2[n] += v;
                x2[n] = fmaxf(x2[n], v);
            }
        }
    }
    // mode1 (per b,co,h): reduce over w = lane&15 groups
    #pragma unroll
    for (int m = 0; m < 4; m++)
        #pragma unroll
        for (int r = 0; r < 4; r++) {
            float s = t1s[m][r], x = t1m[m][r];
            #pragma unroll
            for (int off = 1; off <= 8; off <<= 1) {
                s += __shfl_xor(s, off);
                x = fmaxf(x, __shfl_xor(x, off));
            }
            t1s[m][r] = s; t1m[m][r] = x;
        }
    if (l15 == 0) {
        #pragma unroll
        for (int m = 0; m < 4; m++)
            #pragma unroll
            for (int r = 0; r < 4; r++) {
                const int co = cob + m * 16 + l4 * 4 + r;
                const int idx = (b * 256 + co) * 128 + h;
                atomicAdd(&p1s[idx], t1s[m][r]);
                atomicMax(&p1m[idx], fkey(t1m[m][r]));
            }
    }
    // mode2 (per b,w): reduce over quads (co), then atomics; accumulate mode3
    float s3 = 0.f, x3 = -INFINITY;
    #pragma unroll
    for (int n = 0; n < 4; n++) {
        float s = s2[n], x = x2[n];
        s += __shfl_xor(s, 16); s += __shfl_xor(s, 32);
        x = fmaxf(x, __shfl_xor(x, 16)); x = fmaxf(x, __shfl_xor(x, 32));
        if (l4 == n) {
            const int w = wn * 64 + n * 16 + l15;
            atomicAdd(&p2s[b * 128 + w], s);
            atomicMax(&p2m[b * 128 + w], fkey(x));
        }
        s3 += s; x3 = fmaxf(x3, x);
    }
    // mode3 (per b,h): reduce over w lanes, one atomic per wave
    #pragma unroll
    for (int off = 1; off <= 8; off <<= 1) {
        s3 += __shfl_xor(s3, off);
        x3 = fmaxf(x3, __shfl_xor(x3, off));
    }
    if (lane == 0) {
        atomicAdd(&p3s[b * 128 + h], s3);
        atomicMax(&p3m[b * 128 + h], fkey(x3));
    }
}

// ---------------------------------------------------------------------------
// K3: tiny per-batch kernel: coefficients, U1/U2/U3, V1, spec. grid(8) x 256.
// ---------------------------------------------------------------------------
__device__ inline float blockSum256(float v, float* red)
{
    #pragma unroll
    for (int off = 32; off >= 1; off >>= 1) v += __shfl_xor(v, off);
    const int wave = threadIdx.x >> 6, lane = threadIdx.x & 63;
    __syncthreads();
    if (lane == 0) red[wave] = v;
    __syncthreads();
    return red[0] + red[1] + red[2] + red[3];
}

__device__ inline void softmax4(const float* A, const float* M, const float* Bc,
                                float avg, float mx, float* u)
{
    float l0 = fmaf(A[0], avg, fmaf(M[0], mx, Bc[0]));
    float l1 = fmaf(A[1], avg, fmaf(M[1], mx, Bc[1]));
    float l2 = fmaf(A[2], avg, fmaf(M[2], mx, Bc[2]));
    float l3 = fmaf(A[3], avg, fmaf(M[3], mx, Bc[3]));
    const float mm = fmaxf(fmaxf(l0, l1), fmaxf(l2, l3));
    const float e0 = expf(l0 - mm), e1 = expf(l1 - mm);
    const float e2 = expf(l2 - mm), e3 = expf(l3 - mm);
    const float inv = 1.f / (e0 + e1 + e2 + e3);
    u[0] = e0 * inv; u[1] = e1 * inv; u[2] = e2 * inv; u[3] = e3 * inv;
}

__global__ void make_u_kernel(
    const float* __restrict__ p1s, const unsigned* __restrict__ p1m,
    const float* __restrict__ p2s, const unsigned* __restrict__ p2m,
    const float* __restrict__ p3s, const unsigned* __restrict__ p3m,
    const float* __restrict__ a1w, const float* __restrict__ a1b,
    const float* __restrict__ a2w, const float* __restrict__ a2b,
    const float* __restrict__ a3w, const float* __restrict__ a3b,
    const float* __restrict__ ugw, const float* __restrict__ ugb,
    const float* __restrict__ rw,
    const float* __restrict__ spaw, const float* __restrict__ spab,
    const float* __restrict__ spmw, const float* __restrict__ spmb,
    float* __restrict__ U2g, float* __restrict__ U3g,
    float* __restrict__ V1g, float* __restrict__ specg)
{
    const int b = blockIdx.x, tid = threadIdx.x;

    __shared__ float red[4];
    __shared__ float coefA[3][4], coefM[3][4], coefB[3][4];
    __shared__ float U1s[256][4], U2s[128][4], U3s[128][4];
    __shared__ float gavg[256], gmax[256];

    const float* aws[3]  = { a1w, a2w, a3w };
    const float* abs_[3] = { a1b, a2b, a3b };
    for (int m = 0; m < 3; m++) {
        for (int k = 0; k < 4; k++) {
            const float u = ugw[k * 256 + tid];
            float va = u * aws[m][tid * 2 + 0];
            float vm = u * aws[m][tid * 2 + 1];
            float vb = u * abs_[m][tid];
            va = blockSum256(va, red);
            vm = blockSum256(vm, red);
            vb = blockSum256(vb, red);
            if (tid == 0) {
                coefA[m][k] = va; coefM[m][k] = vm; coefB[m][k] = vb + ugb[k];
            }
        }
    }
    __syncthreads();

    // U1 (per-c): gather over h partials
    {
        const float* ps = p1s + ((size_t)b * 256 + tid) * 128;
        const unsigned* pm = p1m + ((size_t)b * 256 + tid) * 128;
        float s = 0.f, mx = -INFINITY;
        for (int hh = 0; hh < 128; hh++) {
            s += ps[hh];
            mx = fmaxf(mx, fkeydec(pm[hh]));
        }
        float u[4];
        softmax4(coefA[0], coefM[0], coefB[0], s * (1.f / 16384.f), mx, u);
        U1s[tid][0] = u[0]; U1s[tid][1] = u[1]; U1s[tid][2] = u[2]; U1s[tid][3] = u[3];
    }
    // U2 (per-w) / U3 (per-h)
    if (tid < 128) {
        const float avg = p2s[b * 128 + tid] * (1.f / 32768.f);
        const float mx  = fkeydec(p2m[b * 128 + tid]);
        float u[4];
        softmax4(coefA[1], coefM[1], coefB[1], avg, mx, u);
        float* g = U2g + ((size_t)b * 128 + tid) * 4;
        for (int k = 0; k < 4; k++) { U2s[tid][k] = u[k]; g[k] = u[k]; }
    } else {
        const int hh = tid - 128;
        const float avg = p3s[b * 128 + hh] * (1.f / 32768.f);
        const float mx  = fkeydec(p3m[b * 128 + hh]);
        float u[4];
        softmax4(coefA[2], coefM[2], coefB[2], avg, mx, u);
        float* g = U3g + ((size_t)b * 128 + hh) * 4;
        for (int k = 0; k < 4; k++) { U3s[hh][k] = u[k]; g[k] = u[k]; }
    }
    __syncthreads();

    // V1[b,o,k] = sum_c recon_w[o,c] * U1[b,c,k]
    {
        float v0 = 0.f, v1 = 0.f, v2 = 0.f, v3 = 0.f;
        const float* rrow = rw + (size_t)tid * 256;
        for (int c2 = 0; c2 < 256; c2++) {
            const float r = rrow[c2];
            v0 = fmaf(r, U1s[c2][0], v0);
            v1 = fmaf(r, U1s[c2][1], v1);
            v2 = fmaf(r, U1s[c2][2], v2);
            v3 = fmaf(r, U1s[c2][3], v3);
        }
        float* vp = V1g + ((size_t)b * 256 + tid) * 4;
        vp[0] = v0; vp[1] = v1; vp[2] = v2; vp[3] = v3;
    }
    // F_spe stats
    {
        const float a0 = U1s[tid][0], a1 = U1s[tid][1];
        const float a2 = U1s[tid][2], a3 = U1s[tid][3];
        float s = 0.f, m = -INFINITY;
        for (int n = 0; n < 256; n++) {
            const float* u23 = (n < 128) ? U2s[n] : U3s[n - 128];
            const float val = a0 * u23[0] + a1 * u23[1] + a2 * u23[2] + a3 * u23[3];
            s += val; m = fmaxf(m, val);
        }
        gavg[tid] = s * (1.f / 256.f);
        gmax[tid] = m;
    }
    __syncthreads();
    // spec
    {
        float s = spab[tid] + spmb[tid];
        const float* wa = spaw + (size_t)tid * 256;
        const float* wmp = spmw + (size_t)tid * 256;
        for (int c2 = 0; c2 < 256; c2++) {
            s = fmaf(gavg[c2], wa[c2], s);
            s = fmaf(gmax[c2], wmp[c2], s);
        }
        float sg = 1.f / (1.f + expf(-s));
        sg = 1.f / (1.f + expf(-sg));
        specg[b * 256 + tid] = sg;
    }
}

// ---------------------------------------------------------------------------
// K4: final fused output + CP recon. block 256 = (w 128, c-sub 2).
// ---------------------------------------------------------------------------
__global__ __launch_bounds__(256) void final_kernel(
    const float* __restrict__ frm, const float* __restrict__ oth,
    const float* __restrict__ U2g, const float* __restrict__ U3g,
    const float* __restrict__ V1g, const float* __restrict__ specg,
    const float* __restrict__ rb,  const float* __restrict__ spw,
    const float* __restrict__ spb, const float* __restrict__ alphap,
    float* __restrict__ out)
{
    const int w  = threadIdx.x & 127;
    const int cc = threadIdx.x >> 7;
    const int h  = blockIdx.x;
    const int c  = blockIdx.y * 2 + cc;
    const int b  = blockIdx.z;

    const float4 u2 = *(const float4*)(U2g + ((size_t)b * 128 + w) * 4);
    const float4 u3 = *(const float4*)(U3g + ((size_t)b * 128 + h) * 4);
    const float4 v1 = *(const float4*)(V1g + ((size_t)b * 256 + c) * 4);

    const float p0 = u2.x * u3.x, p1 = u2.y * u3.y;
    const float p2 = u2.z * u3.z, p3 = u2.w * u3.w;
    const float dot = p0 + p1 + p2 + p3;
    const float att = 1.f / (1.f + expf(-(spw[0] * dot + spb[0])));
    const float cp  = v1.x * p0 + v1.y * p1 + v1.z * p2 + v1.w * p3 + rb[c];

    const float spec  = specg[b * 256 + c];
    const float Watt  = spec * att;
    const float alpha = alphap[0];

    const size_t idx = (((size_t)b * 256 + c) << 14) + ((size_t)h << 7) + w;
    const float f = frm[idx], o = oth[idx];
    out[idx]          = alpha * Watt * f + (1.f - alpha) * (1.f - Watt) * o;
    out[CP_OFF + idx] = cp;
}

// ---------------------------------------------------------------------------
extern "C" void kernel_launch(void* const* d_in, const int* in_sizes, int n_in,
                              void* d_out, int out_size, void* d_ws, size_t ws_size,
                              hipStream_t stream)
{
    const float* frm   = (const float*)d_in[0];
    const float* oth   = (const float*)d_in[1];
    const float* cw    = (const float*)d_in[2];
    const float* cb    = (const float*)d_in[3];
    const float* a1w   = (const float*)d_in[4];
    const float* a1b   = (const float*)d_in[5];
    const float* a2w   = (const float*)d_in[6];
    const float* a2b   = (const float*)d_in[7];
    const float* a3w   = (const float*)d_in[8];
    const float* a3b   = (const float*)d_in[9];
    const float* ugw   = (const float*)d_in[10];
    const float* ugb   = (const float*)d_in[11];
    const float* rw    = (const float*)d_in[12];
    const float* rb    = (const float*)d_in[13];
    const float* spw   = (const float*)d_in[14];
    const float* spb   = (const float*)d_in[15];
    const float* spaw  = (const float*)d_in[16];
    const float* spab  = (const float*)d_in[17];
    const float* spmw  = (const float*)d_in[18];
    const float* spmb  = (const float*)d_in[19];
    const float* alpha = (const float*)d_in[20];

    float* out = (float*)d_out;
    float* ws  = (float*)d_ws;

    unsigned short* Wt = (unsigned short*)out;              // 2.36 MB in main half
    unsigned short* Xt = (unsigned short*)(out + CP_OFF);   // 134 MB in cp half

    float*    zb  = ws + ZB_OFF;
    float*    p1s = ws + P1S_OFF;
    unsigned* p1m = (unsigned*)(ws + P1M_OFF);
    float*    p2s = ws + P2S_OFF;
    unsigned* p2m = (unsigned*)(ws + P2M_OFF);
    float*    p3s = ws + P3S_OFF;
    unsigned* p3m = (unsigned*)(ws + P3M_OFF);
    float*    U2g = ws + U2_OFF;
    float*    U3g = ws + U3_OFF;
    float*    V1g = ws + V1_OFF;
    float*    spc = ws + SPEC_OFF;

    // zero zbuf + reduction partials (max keys: 0 == -inf)
    hipMemsetAsync(d_ws, 0, WS_ZERO_BYTES, stream);

    // prep: bf16 operand layouts (staged in d_out, overwritten by final)
    wt_kernel<<<dim3(512), 256, 0, stream>>>(cw, Wt);
    xt_kernel<<<dim3(HH, BB), 256, 0, stream>>>(frm, oth, Xt);

    // conv + fused reductions (1D grid, XCD-swizzled inside the kernel)
    conv_mfma<<<dim3(2048), 256, 0, stream>>>(
        Wt, Xt, cb, (const unsigned short*)zb,
        p1s, p1m, p2s, p2m, p3s, p3m);

    // U / V1 / spec
    make_u_kernel<<<dim3(BB), 256, 0, stream>>>(
        p1s, p1m, p2s, p2m, p3s, p3m,
        a1w, a1b, a2w, a2b, a3w, a3b, ugw, ugb,
        rw, spaw, spab, spmw, spmb,
        U2g, U3g, V1g, spc);

    // fused output + cp (overwrites Wt/Xt staging areas last)
    final_kernel<<<dim3(HH, CC / 2, BB), 256, 0, stream>>>(
        frm, oth, U2g, U3g, V1g, spc, rb, spw, spb, alpha, out);
}

// Round 3
// 1018.298 us; speedup vs baseline: 1.1207x; 1.1207x over previous
//
#include <hip/hip_runtime.h>
#include <math.h>

// Problem constants
#define BB 8
#define CC 256
#define HH 128
#define WW 128
#define CP_OFF 33554432          // floats; cp half of d_out

// ---- workspace layout (float offsets) ----
#define ZB_OFF   0               // 256 floats of zeros (OOB load target)
#define P1S_OFF  256             // [8][256][128] f32
#define P1M_OFF  262400          // [8][256][128] u32 (ordered-key max)
#define P2S_OFF  524544          // [8][128]
#define P2M_OFF  525568          // [8][128]
#define P3S_OFF  526592          // [8][128]
#define P3M_OFF  527616          // [8][128]
#define U2_OFF   528640          // [8][128][4]
#define U3_OFF   532736          // [8][128][4]
#define V1_OFF   536832          // [8][256][4]
#define SPEC_OFF 545024          // [8][256]
#define WS_ZERO_BYTES (528640 * 4)   // zero zbuf + all reduction partials

typedef __attribute__((ext_vector_type(8))) short bf16x8;
typedef __attribute__((ext_vector_type(4))) float f32x4;

// ---------------- helpers ----------------
static __device__ __forceinline__ unsigned short f2bf(float f) {
    unsigned u = __float_as_uint(f);
    unsigned r = u + 0x7FFFu + ((u >> 16) & 1u);   // RNE
    return (unsigned short)(r >> 16);
}
static __device__ __forceinline__ unsigned fkey(float f) {
    unsigned u = __float_as_uint(f);
    return (u & 0x80000000u) ? ~u : (u | 0x80000000u);
}
static __device__ __forceinline__ float fkeydec(unsigned k) {
    return __uint_as_float((k & 0x80000000u) ? (k & 0x7FFFFFFFu) : ~k);
}
// async 16B global -> LDS. HW semantics: LDS dest = wave-uniform base +
// lane*16 (we pass the uniform base); global src is per-lane.
static __device__ __forceinline__ void gl_lds16(const void* g, void* l) {
    typedef const __attribute__((address_space(1))) unsigned int* gas_t;
    typedef __attribute__((address_space(3))) unsigned int* las_t;
    gas_t gp = (gas_t)(uintptr_t)g;
    las_t lp = (las_t)(unsigned int)(uintptr_t)l;
    __builtin_amdgcn_global_load_lds(gp, lp, 16, 0, 0);
}

// ---------------------------------------------------------------------------
// P1: weights fp32 [co 256][ci 512][3][3] -> WtF fragment layout:
//   [q = kh*16+cic (48)][kw 3][frag fg 16][lane 64][e 8] bf16
// where fg = co>>4, lane = ci-oct(2b)*16 + co&15, e = ci&7.
// Each MFMA A-fragment is then ONE contiguous 1 KB wave load from L2.
// ---------------------------------------------------------------------------
__global__ __launch_bounds__(256) void wt_kernel(
    const float* __restrict__ cw, unsigned short* __restrict__ WtF)
{
    const int g = blockIdx.x * 256 + threadIdx.x;    // 0..131071 = co*512+ci
    const int co = g >> 9, ci = g & 511;
    const int fg = co >> 4, l15c = co & 15;
    const int cic = ci >> 5, l4c = (ci >> 3) & 3, e = ci & 7;
    const int lane = l4c * 16 + l15c;
    const float* s = cw + (size_t)g * 9;
    #pragma unroll
    for (int kh = 0; kh < 3; kh++)
        #pragma unroll
        for (int kw = 0; kw < 3; kw++) {
            const size_t dst =
                ((((size_t)(kh * 16 + cic) * 3 + kw) * 16 + fg) * 64 + lane) * 8 + e;
            WtF[dst] = f2bf(s[kh * 3 + kw]);
        }
}

// ---------------------------------------------------------------------------
// P2: X transpose: frm/oth fp32 [b][c][h][w] -> Xt bf16 [b][h][w][ci 512]
// ---------------------------------------------------------------------------
__global__ __launch_bounds__(256) void xt_kernel(
    const float* __restrict__ frm, const float* __restrict__ oth,
    unsigned short* __restrict__ Xt)
{
    const int w = threadIdx.x & 127, half = threadIdx.x >> 7;
    const int h = blockIdx.x, b = blockIdx.y;
    const float* src = half ? oth : frm;
    const size_t inbase = (((size_t)b * 256) << 14) + ((size_t)h << 7) + w;
    unsigned short* op = Xt + ((((size_t)(b * 128 + h) * 128) + w) << 9) + half * 256;
    #pragma unroll 2
    for (int c8 = 0; c8 < 32; c8++) {
        unsigned short u[8];
        #pragma unroll
        for (int j = 0; j < 8; j++)
            u[j] = f2bf(src[inbase + (((size_t)(c8 * 8 + j)) << 14)]);
        uint4 pk;
        pk.x = (unsigned)u[0] | ((unsigned)u[1] << 16);
        pk.y = (unsigned)u[2] | ((unsigned)u[3] << 16);
        pk.z = (unsigned)u[4] | ((unsigned)u[5] << 16);
        pk.w = (unsigned)u[6] | ((unsigned)u[7] << 16);
        *(uint4*)(op + c8 * 8) = pk;
    }
}

// ---------------------------------------------------------------------------
// K1: MFMA implicit-GEMM conv + bias + leaky + fused mode reductions.
// Tile: 128 co x 128 px (one h-row of one b). grid 2048 (XCD-swizzled),
// block 256 (4 waves in 2x2).
// A operands: DIRECT from L2 (WtF fragment layout, 12 coalesced 1KB wave
// loads -> VGPR per chunk, double-buffered in rA0/rA1). A never touches
// LDS -> LDS pipe (the per-CU bottleneck) carries only B.
// B operands: Xt rows staged to LDS via global_load_lds, double-buffered,
// 3 DMA instr/wave/chunk. Counted vmcnt(15) = next chunk's 3 B + 12 A.
// ---------------------------------------------------------------------------
__global__ __launch_bounds__(256, 2) void conv_mfma(
    const unsigned short* __restrict__ WtF,
    const unsigned short* __restrict__ Xt,
    const float* __restrict__ cb,
    const unsigned short* __restrict__ zb,
    float* __restrict__ p1s, unsigned* __restrict__ p1m,
    float* __restrict__ p2s, unsigned* __restrict__ p2m,
    float* __restrict__ p3s, unsigned* __restrict__ p3m)
{
    // B: 4 rows (ku) x 136-unit stride (16B units)
    __shared__ __align__(16) unsigned short lB[2][544 * 8];    // 2 x 8704 B

    const int tid = threadIdx.x;
    // XCD-aware swizzle: XCD k owns batch k's panel, h-major, cohalf-adjacent
    const int swz = (blockIdx.x & 7) * 256 + (blockIdx.x >> 3);
    const int b = swz >> 8;
    const int h = (swz >> 1) & 127;
    const int cohalf = swz & 1;

    const int lane = tid & 63, wid = tid >> 6;
    const int wm = wid & 1, wn = wid >> 1;
    const int l15 = lane & 15, l4 = lane >> 4;
    const int fgBase = cohalf * 8 + wm * 4;       // frag id base for this wave

    // ---- staging precompute (hoisted) ----
    // B: wave wid stages row ku = wid; 3 instructions (2 full + 8-lane tail)
    const unsigned short* baseB[3];
    bool okB[3];
    int dstB[3];
    #pragma unroll
    for (int j = 0; j < 3; j++) {
        const int wi = j * 64 + lane;
        const int wg = wi - 1;
        okB[j] = (wg >= 0) && (wg < WW);
        baseB[j] = Xt + (size_t)b * 8388608
                      + (size_t)(okB[j] ? wg : 0) * 512 + wid * 8;
        dstB[j] = (wid * 136 + j * 64) * 8;
    }
    // A: per-wave fragment base (frag = contiguous 1KB: 64 lanes x 16B)
    const unsigned short* baseA = WtF + (size_t)fgBase * 512 + (size_t)lane * 8;

    f32x4 acc[4][4];
    #pragma unroll
    for (int m = 0; m < 4; m++)
        #pragma unroll
        for (int n = 0; n < 4; n++)
            acc[m][n] = (f32x4){0.f, 0.f, 0.f, 0.f};

    // stage B for chunk q (kh = q>>4, ci0 = (q&15)*32): 3 VMEM instr/wave
    auto stageB = [&](int q, int bufi) {
        const int kh = q >> 4;
        const int ci0 = (q & 15) << 5;
        const int hr = h + kh - 1;
        const bool hv = (hr >= 0) && (hr < HH);
        const int boff = (hv ? hr : 0) * 65536 + ci0;
        #pragma unroll
        for (int j = 0; j < 2; j++) {
            const unsigned short* s = (hv && okB[j]) ? (baseB[j] + boff) : zb;
            gl_lds16(s, &lB[bufi][dstB[j]]);
        }
        {   // tail: 8 active lanes (wi 128..135)
            const unsigned short* s = (hv && okB[2]) ? (baseB[2] + boff) : zb;
            if (lane < 8) gl_lds16(s, &lB[bufi][dstB[2]]);
        }
    };

    // load A fragments for chunk q into statically-indexed register array
    auto loadA = [&](int q, bf16x8 (&r)[12]) {
        const unsigned short* p = baseA + (size_t)q * 24576;
        #pragma unroll
        for (int kw = 0; kw < 3; kw++)
            #pragma unroll
            for (int m = 0; m < 4; m++)
                r[kw * 4 + m] = *(const bf16x8*)(p + kw * 8192 + m * 512);
    };

    auto compute = [&](const unsigned short* Bl, bf16x8 (&rA)[12]) {
        #pragma unroll
        for (int kw = 0; kw < 3; kw++) {
            bf16x8 bfr[4];
            #pragma unroll
            for (int n = 0; n < 4; n++) {
                const int unit = l4 * 136 + wn * 64 + n * 16 + l15 + kw;
                bfr[n] = *(const bf16x8*)&Bl[unit * 8];
            }
            #pragma unroll
            for (int m = 0; m < 4; m++)
                #pragma unroll
                for (int n = 0; n < 4; n++)
                    acc[m][n] = __builtin_amdgcn_mfma_f32_16x16x32_bf16(
                        rA[kw * 4 + m], bfr[n], acc[m][n], 0, 0, 0);
        }
    };

    bf16x8 rA0[12], rA1[12];

    // prologue: chunk 0
    stageB(0, 0);
    loadA(0, rA0);

    #pragma unroll 1
    for (int q = 0; q < 46; q += 2) {
        // ---- even half: prefetch q+1, compute q (buf0, rA0) ----
        stageB(q + 1, 1);
        loadA(q + 1, rA1);
        __builtin_amdgcn_sched_barrier(0);
        asm volatile("s_waitcnt vmcnt(15)" ::: "memory");  // chunk q landed
        __builtin_amdgcn_s_barrier();
        __builtin_amdgcn_sched_barrier(0);
        __builtin_amdgcn_s_setprio(1);
        compute(lB[0], rA0);
        __builtin_amdgcn_s_setprio(0);
        __builtin_amdgcn_sched_barrier(0);
        __builtin_amdgcn_s_barrier();                      // gate buf0 reuse

        // ---- odd half: prefetch q+2, compute q+1 (buf1, rA1) ----
        stageB(q + 2, 0);
        loadA(q + 2, rA0);
        __builtin_amdgcn_sched_barrier(0);
        asm volatile("s_waitcnt vmcnt(15)" ::: "memory");  // chunk q+1 landed
        __builtin_amdgcn_s_barrier();
        __builtin_amdgcn_sched_barrier(0);
        __builtin_amdgcn_s_setprio(1);
        compute(lB[1], rA1);
        __builtin_amdgcn_s_setprio(0);
        __builtin_amdgcn_sched_barrier(0);
        __builtin_amdgcn_s_barrier();                      // gate buf1 reuse
    }
    // tail: chunks 46 (in buf0/rA0) and 47
    stageB(47, 1);
    loadA(47, rA1);
    __builtin_amdgcn_sched_barrier(0);
    asm volatile("s_waitcnt vmcnt(15)" ::: "memory");      // chunk 46 landed
    __builtin_amdgcn_s_barrier();
    __builtin_amdgcn_sched_barrier(0);
    __builtin_amdgcn_s_setprio(1);
    compute(lB[0], rA0);
    __builtin_amdgcn_s_setprio(0);
    __builtin_amdgcn_sched_barrier(0);
    asm volatile("s_waitcnt vmcnt(0)" ::: "memory");       // chunk 47 landed
    __builtin_amdgcn_s_barrier();
    __builtin_amdgcn_s_setprio(1);
    compute(lB[1], rA1);
    __builtin_amdgcn_s_setprio(0);

    // ---- epilogue: bias + LeakyReLU, then fused mode reductions ----
    // D layout: co = cob + m*16 + l4*4 + r ; px(w) = wn*64 + n*16 + l15
    const int cob = cohalf * 128 + wm * 64;
    float t1s[4][4], t1m[4][4], s2[4], x2[4];
    #pragma unroll
    for (int n = 0; n < 4; n++) { s2[n] = 0.f; x2[n] = -INFINITY; }

    #pragma unroll
    for (int m = 0; m < 4; m++) {
        const float4 bb4 = *(const float4*)&cb[cob + m * 16 + l4 * 4];
        float bbv[4] = { bb4.x, bb4.y, bb4.z, bb4.w };
        #pragma unroll
        for (int r = 0; r < 4; r++) { t1s[m][r] = 0.f; t1m[m][r] = -INFINITY; }
        #pragma unroll
        for (int n = 0; n < 4; n++) {
            #pragma unroll
            for (int r = 0; r < 4; r++) {
                float v = acc[m][n][r] + bbv[r];
                v = (v >= 0.f) ? v : 0.01f * v;
                t1s[m][r] += v;
                t1m[m][r] = fmaxf(t1m[m][r], v);
                s2[n] += v;
                x2[n] = fmaxf(x2[n], v);
            }
        }
    }
    // mode1 (per b,co,h): reduce over w = lane&15 groups
    #pragma unroll
    for (int m = 0; m < 4; m++)
        #pragma unroll
        for (int r = 0; r < 4; r++) {
            float s = t1s[m][r], x = t1m[m][r];
            #pragma unroll
            for (int off = 1; off <= 8; off <<= 1) {
                s += __shfl_xor(s, off);
                x = fmaxf(x, __shfl_xor(x, off));
            }
            t1s[m][r] = s; t1m[m][r] = x;
        }
    if (l15 == 0) {
        #pragma unroll
        for (int m = 0; m < 4; m++)
            #pragma unroll
            for (int r = 0; r < 4; r++) {
                const int co = cob + m * 16 + l4 * 4 + r;
                const int idx = (b * 256 + co) * 128 + h;
                atomicAdd(&p1s[idx], t1s[m][r]);
                atomicMax(&p1m[idx], fkey(t1m[m][r]));
            }
    }
    // mode2 (per b,w): reduce over quads (co), then atomics; accumulate mode3
    float s3 = 0.f, x3 = -INFINITY;
    #pragma unroll
    for (int n = 0; n < 4; n++) {
        float s = s2[n], x = x2[n];
        s += __shfl_xor(s, 16); s += __shfl_xor(s, 32);
        x = fmaxf(x, __shfl_xor(x, 16)); x = fmaxf(x, __shfl_xor(x, 32));
        if (l4 == n) {
            const int w = wn * 64 + n * 16 + l15;
            atomicAdd(&p2s[b * 128 + w], s);
            atomicMax(&p2m[b * 128 + w], fkey(x));
        }
        s3 += s; x3 = fmaxf(x3, x);
    }
    // mode3 (per b,h): reduce over w lanes, one atomic per wave
    #pragma unroll
    for (int off = 1; off <= 8; off <<= 1) {
        s3 += __shfl_xor(s3, off);
        x3 = fmaxf(x3, __shfl_xor(x3, off));
    }
    if (lane == 0) {
        atomicAdd(&p3s[b * 128 + h], s3);
        atomicMax(&p3m[b * 128 + h], fkey(x3));
    }
}

// ---------------------------------------------------------------------------
// K3: tiny per-batch kernel: coefficients, U1/U2/U3, V1, spec. grid(8) x 256.
// ---------------------------------------------------------------------------
__device__ inline float blockSum256(float v, float* red)
{
    #pragma unroll
    for (int off = 32; off >= 1; off >>= 1) v += __shfl_xor(v, off);
    const int wave = threadIdx.x >> 6, lane = threadIdx.x & 63;
    __syncthreads();
    if (lane == 0) red[wave] = v;
    __syncthreads();
    return red[0] + red[1] + red[2] + red[3];
}

__device__ inline void softmax4(const float* A, const float* M, const float* Bc,
                                float avg, float mx, float* u)
{
    float l0 = fmaf(A[0], avg, fmaf(M[0], mx, Bc[0]));
    float l1 = fmaf(A[1], avg, fmaf(M[1], mx, Bc[1]));
    float l2 = fmaf(A[2], avg, fmaf(M[2], mx, Bc[2]));
    float l3 = fmaf(A[3], avg, fmaf(M[3], mx, Bc[3]));
    const float mm = fmaxf(fmaxf(l0, l1), fmaxf(l2, l3));
    const float e0 = expf(l0 - mm), e1 = expf(l1 - mm);
    const float e2 = expf(l2 - mm), e3 = expf(l3 - mm);
    const float inv = 1.f / (e0 + e1 + e2 + e3);
    u[0] = e0 * inv; u[1] = e1 * inv; u[2] = e2 * inv; u[3] = e3 * inv;
}

__global__ void make_u_kernel(
    const float* __restrict__ p1s, const unsigned* __restrict__ p1m,
    const float* __restrict__ p2s, const unsigned* __restrict__ p2m,
    const float* __restrict__ p3s, const unsigned* __restrict__ p3m,
    const float* __restrict__ a1w, const float* __restrict__ a1b,
    const float* __restrict__ a2w, const float* __restrict__ a2b,
    const float* __restrict__ a3w, const float* __restrict__ a3b,
    const float* __restrict__ ugw, const float* __restrict__ ugb,
    const float* __restrict__ rw,
    const float* __restrict__ spaw, const float* __restrict__ spab,
    const float* __restrict__ spmw, const float* __restrict__ spmb,
    float* __restrict__ U2g, float* __restrict__ U3g,
    float* __restrict__ V1g, float* __restrict__ specg)
{
    const int b = blockIdx.x, tid = threadIdx.x;

    __shared__ float red[4];
    __shared__ float coefA[3][4], coefM[3][4], coefB[3][4];
    __shared__ float U1s[256][4], U2s[128][4], U3s[128][4];
    __shared__ float gavg[256], gmax[256];

    const float* aws[3]  = { a1w, a2w, a3w };
    const float* abs_[3] = { a1b, a2b, a3b };
    for (int m = 0; m < 3; m++) {
        for (int k = 0; k < 4; k++) {
            const float u = ugw[k * 256 + tid];
            float va = u * aws[m][tid * 2 + 0];
            float vm = u * aws[m][tid * 2 + 1];
            float vb = u * abs_[m][tid];
            va = blockSum256(va, red);
            vm = blockSum256(vm, red);
            vb = blockSum256(vb, red);
            if (tid == 0) {
                coefA[m][k] = va; coefM[m][k] = vm; coefB[m][k] = vb + ugb[k];
            }
        }
    }
    __syncthreads();

    // U1 (per-c): gather over h partials
    {
        const float* ps = p1s + ((size_t)b * 256 + tid) * 128;
        const unsigned* pm = p1m + ((size_t)b * 256 + tid) * 128;
        float s = 0.f, mx = -INFINITY;
        for (int hh = 0; hh < 128; hh++) {
            s += ps[hh];
            mx = fmaxf(mx, fkeydec(pm[hh]));
        }
        float u[4];
        softmax4(coefA[0], coefM[0], coefB[0], s * (1.f / 16384.f), mx, u);
        U1s[tid][0] = u[0]; U1s[tid][1] = u[1]; U1s[tid][2] = u[2]; U1s[tid][3] = u[3];
    }
    // U2 (per-w) / U3 (per-h)
    if (tid < 128) {
        const float avg = p2s[b * 128 + tid] * (1.f / 32768.f);
        const float mx  = fkeydec(p2m[b * 128 + tid]);
        float u[4];
        softmax4(coefA[1], coefM[1], coefB[1], avg, mx, u);
        float* g = U2g + ((size_t)b * 128 + tid) * 4;
        for (int k = 0; k < 4; k++) { U2s[tid][k] = u[k]; g[k] = u[k]; }
    } else {
        const int hh = tid - 128;
        const float avg = p3s[b * 128 + hh] * (1.f / 32768.f);
        const float mx  = fkeydec(p3m[b * 128 + hh]);
        float u[4];
        softmax4(coefA[2], coefM[2], coefB[2], avg, mx, u);
        float* g = U3g + ((size_t)b * 128 + hh) * 4;
        for (int k = 0; k < 4; k++) { U3s[hh][k] = u[k]; g[k] = u[k]; }
    }
    __syncthreads();

    // V1[b,o,k] = sum_c recon_w[o,c] * U1[b,c,k]
    {
        float v0 = 0.f, v1 = 0.f, v2 = 0.f, v3 = 0.f;
        const float* rrow = rw + (size_t)tid * 256;
        for (int c2 = 0; c2 < 256; c2++) {
            const float r = rrow[c2];
            v0 = fmaf(r, U1s[c2][0], v0);
            v1 = fmaf(r, U1s[c2][1], v1);
            v2 = fmaf(r, U1s[c2][2], v2);
            v3 = fmaf(r, U1s[c2][3], v3);
        }
        float* vp = V1g + ((size_t)b * 256 + tid) * 4;
        vp[0] = v0; vp[1] = v1; vp[2] = v2; vp[3] = v3;
    }
    // F_spe stats
    {
        const float a0 = U1s[tid][0], a1 = U1s[tid][1];
        const float a2 = U1s[tid][2], a3 = U1s[tid][3];
        float s = 0.f, m = -INFINITY;
        for (int n = 0; n < 256; n++) {
            const float* u23 = (n < 128) ? U2s[n] : U3s[n - 128];
            const float val = a0 * u23[0] + a1 * u23[1] + a2 * u23[2] + a3 * u23[3];
            s += val; m = fmaxf(m, val);
        }
        gavg[tid] = s * (1.f / 256.f);
        gmax[tid] = m;
    }
    __syncthreads();
    // spec
    {
        float s = spab[tid] + spmb[tid];
        const float* wa = spaw + (size_t)tid * 256;
        const float* wmp = spmw + (size_t)tid * 256;
        for (int c2 = 0; c2 < 256; c2++) {
            s = fmaf(gavg[c2], wa[c2], s);
            s = fmaf(gmax[c2], wmp[c2], s);
        }
        float sg = 1.f / (1.f + expf(-s));
        sg = 1.f / (1.f + expf(-sg));
        specg[b * 256 + tid] = sg;
    }
}

// ---------------------------------------------------------------------------
// K4: final fused output + CP recon. block 256 = (w 128, c-sub 2).
// ---------------------------------------------------------------------------
__global__ __launch_bounds__(256) void final_kernel(
    const float* __restrict__ frm, const float* __restrict__ oth,
    const float* __restrict__ U2g, const float* __restrict__ U3g,
    const float* __restrict__ V1g, const float* __restrict__ specg,
    const float* __restrict__ rb,  const float* __restrict__ spw,
    const float* __restrict__ spb, const float* __restrict__ alphap,
    float* __restrict__ out)
{
    const int w  = threadIdx.x & 127;
    const int cc = threadIdx.x >> 7;
    const int h  = blockIdx.x;
    const int c  = blockIdx.y * 2 + cc;
    const int b  = blockIdx.z;

    const float4 u2 = *(const float4*)(U2g + ((size_t)b * 128 + w) * 4);
    const float4 u3 = *(const float4*)(U3g + ((size_t)b * 128 + h) * 4);
    const float4 v1 = *(const float4*)(V1g + ((size_t)b * 256 + c) * 4);

    const float p0 = u2.x * u3.x, p1 = u2.y * u3.y;
    const float p2 = u2.z * u3.z, p3 = u2.w * u3.w;
    const float dot = p0 + p1 + p2 + p3;
    const float att = 1.f / (1.f + expf(-(spw[0] * dot + spb[0])));
    const float cp  = v1.x * p0 + v1.y * p1 + v1.z * p2 + v1.w * p3 + rb[c];

    const float spec  = specg[b * 256 + c];
    const float Watt  = spec * att;
    const float alpha = alphap[0];

    const size_t idx = (((size_t)b * 256 + c) << 14) + ((size_t)h << 7) + w;
    const float f = frm[idx], o = oth[idx];
    out[idx]          = alpha * Watt * f + (1.f - alpha) * (1.f - Watt) * o;
    out[CP_OFF + idx] = cp;
}

// ---------------------------------------------------------------------------
extern "C" void kernel_launch(void* const* d_in, const int* in_sizes, int n_in,
                              void* d_out, int out_size, void* d_ws, size_t ws_size,
                              hipStream_t stream)
{
    const float* frm   = (const float*)d_in[0];
    const float* oth   = (const float*)d_in[1];
    const float* cw    = (const float*)d_in[2];
    const float* cb    = (const float*)d_in[3];
    const float* a1w   = (const float*)d_in[4];
    const float* a1b   = (const float*)d_in[5];
    const float* a2w   = (const float*)d_in[6];
    const float* a2b   = (const float*)d_in[7];
    const float* a3w   = (const float*)d_in[8];
    const float* a3b   = (const float*)d_in[9];
    const float* ugw   = (const float*)d_in[10];
    const float* ugb   = (const float*)d_in[11];
    const float* rw    = (const float*)d_in[12];
    const float* rb    = (const float*)d_in[13];
    const float* spw   = (const float*)d_in[14];
    const float* spb   = (const float*)d_in[15];
    const float* spaw  = (const float*)d_in[16];
    const float* spab  = (const float*)d_in[17];
    const float* spmw  = (const float*)d_in[18];
    const float* spmb  = (const float*)d_in[19];
    const float* alpha = (const float*)d_in[20];

    float* out = (float*)d_out;
    float* ws  = (float*)d_ws;

    unsigned short* Wt = (unsigned short*)out;              // 2.36 MB in main half
    unsigned short* Xt = (unsigned short*)(out + CP_OFF);   // 134 MB in cp half

    float*    zb  = ws + ZB_OFF;
    float*    p1s = ws + P1S_OFF;
    unsigned* p1m = (unsigned*)(ws + P1M_OFF);
    float*    p2s = ws + P2S_OFF;
    unsigned* p2m = (unsigned*)(ws + P2M_OFF);
    float*    p3s = ws + P3S_OFF;
    unsigned* p3m = (unsigned*)(ws + P3M_OFF);
    float*    U2g = ws + U2_OFF;
    float*    U3g = ws + U3_OFF;
    float*    V1g = ws + V1_OFF;
    float*    spc = ws + SPEC_OFF;

    // zero zbuf + reduction partials (max keys: 0 == -inf)
    hipMemsetAsync(d_ws, 0, WS_ZERO_BYTES, stream);

    // prep: bf16 operand layouts (staged in d_out, overwritten by final)
    wt_kernel<<<dim3(512), 256, 0, stream>>>(cw, Wt);
    xt_kernel<<<dim3(HH, BB), 256, 0, stream>>>(frm, oth, Xt);

    // conv + fused reductions (1D grid, XCD-swizzled inside the kernel)
    conv_mfma<<<dim3(2048), 256, 0, stream>>>(
        Wt, Xt, cb, (const unsigned short*)zb,
        p1s, p1m, p2s, p2m, p3s, p3m);

    // U / V1 / spec
    make_u_kernel<<<dim3(BB), 256, 0, stream>>>(
        p1s, p1m, p2s, p2m, p3s, p3m,
        a1w, a1b, a2w, a2b, a3w, a3b, ugw, ugb,
        rw, spaw, spab, spmw, spmb,
        U2g, U3g, V1g, spc);

    // fused output + cp (overwrites Wt/Xt staging areas last)
    final_kernel<<<dim3(HH, CC / 2, BB), 256, 0, stream>>>(
        frm, oth, U2g, U3g, V1g, spc, rb, spw, spb, alpha, out);
}

// Round 4
// 925.503 us; speedup vs baseline: 1.2330x; 1.1003x over previous
//
#include <hip/hip_runtime.h>
#include <math.h>

// Problem constants
#define BB 8
#define CC 256
#define HH 128
#define WW 128
#define CP_OFF 33554432          // floats; cp half of d_out

// ---- workspace layout (float offsets) ----
#define ZB_OFF   0               // 256 floats of zeros (OOB load target)
#define P1S_OFF  256             // [8][256][128] f32 (direct-stored)
#define P1M_OFF  262400          // [8][256][128] u32 fkey (direct-stored)
#define P2S_OFF  524544          // [8][128]
#define P2M_OFF  525568          // [8][128]
#define P3S_OFF  526592          // [8][128]
#define P3M_OFF  527616          // [8][128]
#define U2_OFF   528640          // [8][128][4]
#define U3_OFF   532736          // [8][128][4]
#define V1_OFF   536832          // [8][256][4]
#define SPEC_OFF 545024          // [8][256]
#define WS_ZERO_BYTES (528640 * 4)   // zero zbuf + reduction partials

// scratch parked in d_out main half (free until final_kernel writes):
#define U1G_OUT_OFF 16777216     // [8][256][4] floats (64 MB offset)
#define CF_OUT_OFF  16785408     // [3][4][3] coef floats

typedef __attribute__((ext_vector_type(8))) short bf16x8;
typedef __attribute__((ext_vector_type(4))) float f32x4;

// ---------------- helpers ----------------
static __device__ __forceinline__ unsigned short f2bf(float f) {
    unsigned u = __float_as_uint(f);
    unsigned r = u + 0x7FFFu + ((u >> 16) & 1u);   // RNE
    return (unsigned short)(r >> 16);
}
static __device__ __forceinline__ unsigned fkey(float f) {
    unsigned u = __float_as_uint(f);
    return (u & 0x80000000u) ? ~u : (u | 0x80000000u);
}
static __device__ __forceinline__ float fkeydec(unsigned k) {
    return __uint_as_float((k & 0x80000000u) ? (k & 0x7FFFFFFFu) : ~k);
}
// async 16B global -> LDS. LDS dest = wave-uniform base + lane*16;
// global src is per-lane.
static __device__ __forceinline__ void gl_lds16(const void* g, void* l) {
    typedef const __attribute__((address_space(1))) unsigned int* gas_t;
    typedef __attribute__((address_space(3))) unsigned int* las_t;
    gas_t gp = (gas_t)(uintptr_t)g;
    las_t lp = (las_t)(unsigned int)(uintptr_t)l;
    __builtin_amdgcn_global_load_lds(gp, lp, 16, 0, 0);
}

// ---------------------------------------------------------------------------
// P1: weights fp32 [co 256][ci 512][3][3] -> WtF fragment layout:
//   [q = kh*16+cic (48)][kw 3][fg 16][lane 64][e 8] bf16
// fg = co>>4, lane = ((ci>>3)&3)*16 + (co&15), e = ci&7.
// Each MFMA A-fragment is ONE contiguous 1 KB wave load from L2.
// ---------------------------------------------------------------------------
__global__ __launch_bounds__(256) void wt_kernel(
    const float* __restrict__ cw, unsigned short* __restrict__ WtF)
{
    const int g = blockIdx.x * 256 + threadIdx.x;    // 0..131071 = co*512+ci
    const int co = g >> 9, ci = g & 511;
    const int fg = co >> 4, l15c = co & 15;
    const int cic = ci >> 5, l4c = (ci >> 3) & 3, e = ci & 7;
    const int lane = l4c * 16 + l15c;
    const float* s = cw + (size_t)g * 9;
    #pragma unroll
    for (int kh = 0; kh < 3; kh++)
        #pragma unroll
        for (int kw = 0; kw < 3; kw++) {
            const size_t dst =
                ((((size_t)(kh * 16 + cic) * 3 + kw) * 16 + fg) * 64 + lane) * 8 + e;
            WtF[dst] = f2bf(s[kh * 3 + kw]);
        }
}

// ---------------------------------------------------------------------------
// P2: X transpose: frm/oth fp32 [b][c][h][w] -> Xt bf16 [b][h][w][ci 512]
// ---------------------------------------------------------------------------
__global__ __launch_bounds__(256) void xt_kernel(
    const float* __restrict__ frm, const float* __restrict__ oth,
    unsigned short* __restrict__ Xt)
{
    const int w = threadIdx.x & 127, half = threadIdx.x >> 7;
    const int h = blockIdx.x, b = blockIdx.y;
    const float* src = half ? oth : frm;
    const size_t inbase = (((size_t)b * 256) << 14) + ((size_t)h << 7) + w;
    unsigned short* op = Xt + ((((size_t)(b * 128 + h) * 128) + w) << 9) + half * 256;
    #pragma unroll 2
    for (int c8 = 0; c8 < 32; c8++) {
        unsigned short u[8];
        #pragma unroll
        for (int j = 0; j < 8; j++)
            u[j] = f2bf(src[inbase + (((size_t)(c8 * 8 + j)) << 14)]);
        uint4 pk;
        pk.x = (unsigned)u[0] | ((unsigned)u[1] << 16);
        pk.y = (unsigned)u[2] | ((unsigned)u[3] << 16);
        pk.z = (unsigned)u[4] | ((unsigned)u[5] << 16);
        pk.w = (unsigned)u[6] | ((unsigned)u[7] << 16);
        *(uint4*)(op + c8 * 8) = pk;
    }
}

// ---------------------------------------------------------------------------
// K1: MFMA implicit-GEMM conv + bias + leaky + fused mode reductions.
// Tile: 128 co x 2 h-rows x 128 w. grid 1024 (XCD-swizzled), block 256
// (4 waves: wm = co-half, row = h-row; each wave 64co x 128px, acc 4x8).
// A: direct L2 loads (WtF fragments), SINGLE-buffered rA[12]; reloaded
//    right after its last MFMA use so next chunk's latency hides behind
//    the barrier + stage phase. A bytes/MFMA halved vs 4-n tile.
// B: 2 Xt rows staged to LDS (dbuf), 5 DMA/wave/chunk, counted vmcnt(5).
// ---------------------------------------------------------------------------
__global__ __launch_bounds__(256, 2) void conv_mfma(
    const unsigned short* __restrict__ WtF,
    const unsigned short* __restrict__ Xt,
    const float* __restrict__ cb,
    const unsigned short* __restrict__ zb,
    float* __restrict__ p1s, unsigned* __restrict__ p1m,
    float* __restrict__ p2s, unsigned* __restrict__ p2m,
    float* __restrict__ p3s, unsigned* __restrict__ p3m)
{
    // B: [row 2][ku 4][wi 136] 16B units = 1088 units per buffer
    __shared__ __align__(16) unsigned short lB[2][1088 * 8];   // 2 x 17408 B

    const int tid = threadIdx.x;
    // XCD swizzle: 1024 % 8 == 0, XCD k owns batch k, h-major
    const int swz = (blockIdx.x & 7) * 128 + (blockIdx.x >> 3);
    const int b = swz >> 7;
    const int h0 = (swz >> 1) & 63;
    const int cohalf = swz & 1;

    const int lane = tid & 63, wid = tid >> 6;
    const int wm = wid & 1, row = wid >> 1;
    const int l15 = lane & 15, l4 = lane >> 4;
    const int hout = h0 * 2 + row;
    const int fgBase = cohalf * 8 + wm * 4;

    // ---- B staging precompute (hoisted). Wave wid fills units
    // [wid*272, wid*272+272): 4 full-wave loads + one 16-lane tail.
    // 272*2 = 544 = row stride -> staging row rB = wid>>1 (uniform).
    const int rB = wid >> 1;
    const unsigned short* baseB[5];
    bool okB[5];
    #pragma unroll
    for (int j = 0; j < 5; j++) {
        const int u = wid * 272 + ((j < 4) ? j * 64 : 256) + lane;
        const int rem = u - rB * 544;
        const int ku = ((unsigned)rem) / 136u;
        const int wi = rem - ku * 136;
        const int wg = wi - 1;
        okB[j] = ((unsigned)wg) < 128u;
        baseB[j] = Xt + (size_t)b * 8388608
                      + (size_t)(okB[j] ? wg : 0) * 512 + ku * 8;
    }
    // A fragment base: frag = contiguous 1KB (64 lanes x 16B)
    const unsigned short* baseA = WtF + (size_t)fgBase * 512 + (size_t)lane * 8;

    f32x4 acc[4][8];
    #pragma unroll
    for (int m = 0; m < 4; m++)
        #pragma unroll
        for (int n = 0; n < 8; n++)
            acc[m][n] = (f32x4){0.f, 0.f, 0.f, 0.f};

    bf16x8 rA[12];

    // stage B rows for chunk q (kh = q>>4, ci0 = (q&15)*32): 5 VMEM/wave
    auto stageB = [&](int q, int bufi) {
        const int kh = q >> 4;
        const int ci0 = (q & 15) << 5;
        const int hr = h0 * 2 + rB + kh - 1;
        const bool hv = (hr >= 0) && (hr < HH);
        const int boff = (hv ? hr : 0) * 65536 + ci0;
        #pragma unroll
        for (int j = 0; j < 4; j++) {
            const unsigned short* s = (hv && okB[j]) ? (baseB[j] + boff) : zb;
            gl_lds16(s, &lB[bufi][(wid * 272 + j * 64) * 8]);
        }
        {
            const unsigned short* s = (hv && okB[4]) ? (baseB[4] + boff) : zb;
            if (lane < 16) gl_lds16(s, &lB[bufi][(wid * 272 + 256) * 8]);
        }
    };

    auto loadA = [&](int q) {
        const unsigned short* p = baseA + (size_t)q * 24576;
        #pragma unroll
        for (int kw = 0; kw < 3; kw++)
            #pragma unroll
            for (int m = 0; m < 4; m++)
                rA[kw * 4 + m] = *(const bf16x8*)(p + kw * 8192 + m * 512);
    };

    auto compute = [&](int cur) {
        const unsigned short* Bl = lB[cur];
        #pragma unroll
        for (int kw = 0; kw < 3; kw++) {
            #pragma unroll
            for (int nh = 0; nh < 2; nh++) {
                bf16x8 bfr[4];
                #pragma unroll
                for (int nn = 0; nn < 4; nn++) {
                    const int unit = row * 544 + l4 * 136
                                   + (nh * 4 + nn) * 16 + l15 + kw;
                    bfr[nn] = *(const bf16x8*)&Bl[unit * 8];
                }
                #pragma unroll
                for (int m = 0; m < 4; m++)
                    #pragma unroll
                    for (int nn = 0; nn < 4; nn++)
                        acc[m][nh * 4 + nn] = __builtin_amdgcn_mfma_f32_16x16x32_bf16(
                            rA[kw * 4 + m], bfr[nn], acc[m][nh * 4 + nn], 0, 0, 0);
            }
        }
    };

    // prologue
    stageB(0, 0);
    loadA(0);

    #pragma unroll 1
    for (int q = 0; q < 47; q++) {
        const int cur = q & 1;
        stageB(q + 1, cur ^ 1);                        // 5 newest in flight
        __builtin_amdgcn_sched_barrier(0);
        // wait chunk q's B (5) + rA(q) (12) = all but the 5 newest
        asm volatile("s_waitcnt vmcnt(5)" ::: "memory");
        __builtin_amdgcn_sched_barrier(0);
        __builtin_amdgcn_s_barrier();                  // publish B(q)
        __builtin_amdgcn_sched_barrier(0);
        __builtin_amdgcn_s_setprio(1);
        compute(cur);
        __builtin_amdgcn_s_setprio(0);
        loadA(q + 1);                                  // WAR: after last rA use
        __builtin_amdgcn_sched_barrier(0);
        __builtin_amdgcn_s_barrier();                  // gate buffer overwrite
    }
    // final chunk
    asm volatile("s_waitcnt vmcnt(0)" ::: "memory");
    __builtin_amdgcn_sched_barrier(0);
    __builtin_amdgcn_s_barrier();
    __builtin_amdgcn_sched_barrier(0);
    __builtin_amdgcn_s_setprio(1);
    compute(1);
    __builtin_amdgcn_s_setprio(0);

    // ---- epilogue: bias + LeakyReLU + fused mode reductions ----
    // D layout: co = cob + m*16 + l4*4 + rr ; w = n*16 + l15 ; h = hout
    const int cob = cohalf * 128 + wm * 64;
    float t1s[4][4], t1m[4][4], s2[8], x2[8];
    #pragma unroll
    for (int n = 0; n < 8; n++) { s2[n] = 0.f; x2[n] = -INFINITY; }

    #pragma unroll
    for (int m = 0; m < 4; m++) {
        const float4 bb4 = *(const float4*)&cb[cob + m * 16 + l4 * 4];
        float bbv[4] = { bb4.x, bb4.y, bb4.z, bb4.w };
        #pragma unroll
        for (int r = 0; r < 4; r++) { t1s[m][r] = 0.f; t1m[m][r] = -INFINITY; }
        #pragma unroll
        for (int n = 0; n < 8; n++) {
            #pragma unroll
            for (int r = 0; r < 4; r++) {
                float v = acc[m][n][r] + bbv[r];
                v = (v >= 0.f) ? v : 0.01f * v;
                t1s[m][r] += v;
                t1m[m][r] = fmaxf(t1m[m][r], v);
                s2[n] += v;
                x2[n] = fmaxf(x2[n], v);
            }
        }
    }
    // mode1 (per b,co,h): reduce over w lanes (l15) -> DIRECT store (unique)
    #pragma unroll
    for (int m = 0; m < 4; m++)
        #pragma unroll
        for (int r = 0; r < 4; r++) {
            float s = t1s[m][r], x = t1m[m][r];
            #pragma unroll
            for (int off = 1; off <= 8; off <<= 1) {
                s += __shfl_xor(s, off);
                x = fmaxf(x, __shfl_xor(x, off));
            }
            t1s[m][r] = s; t1m[m][r] = x;
        }
    if (l15 == 0) {
        #pragma unroll
        for (int m = 0; m < 4; m++)
            #pragma unroll
            for (int r = 0; r < 4; r++) {
                const int co = cob + m * 16 + l4 * 4 + r;
                const int idx = (b * 256 + co) * 128 + hout;
                p1s[idx] = t1s[m][r];
                p1m[idx] = fkey(t1m[m][r]);
            }
    }
    // mode2 (per b,w): reduce over l4 (co quads); all 64 lanes atomic x2
    #pragma unroll
    for (int n = 0; n < 8; n++) {
        s2[n] += __shfl_xor(s2[n], 16); s2[n] += __shfl_xor(s2[n], 32);
        x2[n] = fmaxf(x2[n], __shfl_xor(x2[n], 16));
        x2[n] = fmaxf(x2[n], __shfl_xor(x2[n], 32));
    }
    #pragma unroll
    for (int base = 0; base < 8; base += 4) {
        float sv = s2[base + 0], xv = x2[base + 0];
        if (l4 == 1) { sv = s2[base + 1]; xv = x2[base + 1]; }
        if (l4 == 2) { sv = s2[base + 2]; xv = x2[base + 2]; }
        if (l4 == 3) { sv = s2[base + 3]; xv = x2[base + 3]; }
        const int w = base * 16 + lane;
        atomicAdd(&p2s[b * 128 + w], sv);
        atomicMax(&p2m[b * 128 + w], fkey(xv));
    }
    // mode3 (per b,h): sum over n then lanes; one atomic per wave
    float s3 = 0.f, x3 = -INFINITY;
    #pragma unroll
    for (int n = 0; n < 8; n++) { s3 += s2[n]; x3 = fmaxf(x3, x2[n]); }
    #pragma unroll
    for (int off = 1; off <= 8; off <<= 1) {
        s3 += __shfl_xor(s3, off);
        x3 = fmaxf(x3, __shfl_xor(x3, off));
    }
    if (lane == 0) {
        atomicAdd(&p3s[b * 128 + hout], s3);
        atomicMax(&p3m[b * 128 + hout], fkey(x3));
    }
}

// ---------------------------------------------------------------------------
// helpers for the small kernels
// ---------------------------------------------------------------------------
__device__ inline float blockSum256(float v, float* red)
{
    #pragma unroll
    for (int off = 32; off >= 1; off >>= 1) v += __shfl_xor(v, off);
    const int wave = threadIdx.x >> 6, lane = threadIdx.x & 63;
    __syncthreads();
    if (lane == 0) red[wave] = v;
    __syncthreads();
    return red[0] + red[1] + red[2] + red[3];
}

__device__ inline void softmax4c(const float* cf, int m, float avg, float mx, float* u)
{
    float l[4];
    #pragma unroll
    for (int k = 0; k < 4; k++) {
        const float A = cf[(m * 4 + k) * 3 + 0];
        const float M = cf[(m * 4 + k) * 3 + 1];
        const float B = cf[(m * 4 + k) * 3 + 2];
        l[k] = fmaf(A, avg, fmaf(M, mx, B));
    }
    const float mm = fmaxf(fmaxf(l[0], l[1]), fmaxf(l[2], l[3]));
    const float e0 = expf(l[0] - mm), e1 = expf(l[1] - mm);
    const float e2 = expf(l[2] - mm), e3 = expf(l[3] - mm);
    const float inv = 1.f / (e0 + e1 + e2 + e3);
    u[0] = e0 * inv; u[1] = e1 * inv; u[2] = e2 * inv; u[3] = e3 * inv;
}

// ---------------------------------------------------------------------------
// K0: coefficient kernel (1 block): cf[m][k] = {A,M,B} adapter@ugw folds
// ---------------------------------------------------------------------------
__global__ __launch_bounds__(256) void coef_kernel(
    const float* __restrict__ a1w, const float* __restrict__ a1b,
    const float* __restrict__ a2w, const float* __restrict__ a2b,
    const float* __restrict__ a3w, const float* __restrict__ a3b,
    const float* __restrict__ ugw, const float* __restrict__ ugb,
    float* __restrict__ cf)
{
    const int tid = threadIdx.x;
    __shared__ float red[4];
    const float* aws[3]  = { a1w, a2w, a3w };
    const float* abs_[3] = { a1b, a2b, a3b };
    for (int m = 0; m < 3; m++) {
        for (int k = 0; k < 4; k++) {
            const float u = ugw[k * 256 + tid];
            float va = u * aws[m][tid * 2 + 0];
            float vm = u * aws[m][tid * 2 + 1];
            float vb = u * abs_[m][tid];
            va = blockSum256(va, red);
            vm = blockSum256(vm, red);
            vb = blockSum256(vb, red);
            if (tid == 0) {
                cf[(m * 4 + k) * 3 + 0] = va;
                cf[(m * 4 + k) * 3 + 1] = vm;
                cf[(m * 4 + k) * 3 + 2] = vb + ugb[k];
            }
        }
    }
}

// ---------------------------------------------------------------------------
// K3: U kernel. grid (8, 5): y<4 -> U1 for 64 channels (4 threads/ch),
// y==4 -> U2 (tid<128) + U3 (tid>=128).
// ---------------------------------------------------------------------------
__global__ __launch_bounds__(256) void u_kernel(
    const float* __restrict__ p1s, const unsigned* __restrict__ p1m,
    const float* __restrict__ p2s, const unsigned* __restrict__ p2m,
    const float* __restrict__ p3s, const unsigned* __restrict__ p3m,
    const float* __restrict__ cf,
    float* __restrict__ U1g, float* __restrict__ U2g, float* __restrict__ U3g)
{
    const int b = blockIdx.x, y = blockIdx.y, tid = threadIdx.x;
    if (y < 4) {
        const int c = y * 64 + (tid >> 2);
        const int seg = tid & 3;
        const float* ps = p1s + ((size_t)b * 256 + c) * 128 + seg * 32;
        const unsigned* pm = p1m + ((size_t)b * 256 + c) * 128 + seg * 32;
        float s = 0.f, mx = -INFINITY;
        #pragma unroll 8
        for (int i = 0; i < 32; i++) {
            s += ps[i];
            mx = fmaxf(mx, fkeydec(pm[i]));
        }
        s += __shfl_xor(s, 1); s += __shfl_xor(s, 2);
        mx = fmaxf(mx, __shfl_xor(mx, 1));
        mx = fmaxf(mx, __shfl_xor(mx, 2));
        if (seg == 0) {
            float u[4];
            softmax4c(cf, 0, s * (1.f / 16384.f), mx, u);
            float4* g = (float4*)(U1g + ((size_t)b * 256 + c) * 4);
            *g = make_float4(u[0], u[1], u[2], u[3]);
        }
    } else {
        if (tid < 128) {
            const float avg = p2s[b * 128 + tid] * (1.f / 32768.f);
            const float mx  = fkeydec(p2m[b * 128 + tid]);
            float u[4];
            softmax4c(cf, 1, avg, mx, u);
            float4* g = (float4*)(U2g + ((size_t)b * 128 + tid) * 4);
            *g = make_float4(u[0], u[1], u[2], u[3]);
        } else {
            const int hh = tid - 128;
            const float avg = p3s[b * 128 + hh] * (1.f / 32768.f);
            const float mx  = fkeydec(p3m[b * 128 + hh]);
            float u[4];
            softmax4c(cf, 2, avg, mx, u);
            float4* g = (float4*)(U3g + ((size_t)b * 128 + hh) * 4);
            *g = make_float4(u[0], u[1], u[2], u[3]);
        }
    }
}

// ---------------------------------------------------------------------------
// K3b: post kernel. grid (12): blocks 0..7 = spec for batch b;
// blocks 8..11 = V1 for a 64-o chunk (all batches, U1 staged in LDS).
// ---------------------------------------------------------------------------
__global__ __launch_bounds__(256) void post_kernel(
    const float* __restrict__ U1g, const float* __restrict__ U2g,
    const float* __restrict__ U3g, const float* __restrict__ rw,
    const float* __restrict__ spaw, const float* __restrict__ spab,
    const float* __restrict__ spmw, const float* __restrict__ spmb,
    float* __restrict__ V1g, float* __restrict__ specg)
{
    const int tid = threadIdx.x;
    if (blockIdx.x < 8) {
        const int b = blockIdx.x;
        __shared__ float4 U1s[256];
        __shared__ float4 U23[256];
        __shared__ float gavg[256], gmax[256];
        U1s[tid] = ((const float4*)U1g)[b * 256 + tid];
        U23[tid] = (tid < 128) ? ((const float4*)U2g)[b * 128 + tid]
                               : ((const float4*)U3g)[b * 128 + tid - 128];
        __syncthreads();
        const float4 a = U1s[tid];
        float s = 0.f, m = -INFINITY;
        for (int n = 0; n < 256; n++) {
            const float4 u = U23[n];
            const float val = a.x * u.x + a.y * u.y + a.z * u.z + a.w * u.w;
            s += val; m = fmaxf(m, val);
        }
        gavg[tid] = s * (1.f / 256.f);
        gmax[tid] = m;
        __syncthreads();
        float acc = spab[tid] + spmb[tid];
        const float* wa = spaw + (size_t)tid * 256;
        const float* wm = spmw + (size_t)tid * 256;
        for (int c2 = 0; c2 < 256; c2++) {
            acc = fmaf(gavg[c2], wa[c2], acc);
            acc = fmaf(gmax[c2], wm[c2], acc);
        }
        float sg = 1.f / (1.f + expf(-acc));
        sg = 1.f / (1.f + expf(-sg));
        specg[b * 256 + tid] = sg;
    } else {
        // V1[b,o,k] = sum_c rw[o,c] * U1[b,c,k]
        const int och = blockIdx.x - 8;
        const int o = och * 64 + (tid >> 2);
        const int seg = tid & 3;
        __shared__ float4 U1all[2048];      // [b][c] float4 = 32 KB
        for (int i = tid; i < 2048; i += 256)
            U1all[i] = ((const float4*)U1g)[i];
        __syncthreads();
        f32x4 vac[8];
        #pragma unroll
        for (int bb = 0; bb < 8; bb++) vac[bb] = (f32x4){0.f, 0.f, 0.f, 0.f};
        const float* rrow = rw + (size_t)o * 256 + seg * 64;
        for (int i = 0; i < 64; i++) {
            const float r = rrow[i];
            const int c2 = seg * 64 + i;
            #pragma unroll
            for (int bb = 0; bb < 8; bb++) {
                const float4 u = U1all[bb * 256 + c2];
                vac[bb][0] = fmaf(r, u.x, vac[bb][0]);
                vac[bb][1] = fmaf(r, u.y, vac[bb][1]);
                vac[bb][2] = fmaf(r, u.z, vac[bb][2]);
                vac[bb][3] = fmaf(r, u.w, vac[bb][3]);
            }
        }
        #pragma unroll
        for (int bb = 0; bb < 8; bb++)
            #pragma unroll
            for (int k = 0; k < 4; k++) {
                vac[bb][k] += __shfl_xor(vac[bb][k], 1);
                vac[bb][k] += __shfl_xor(vac[bb][k], 2);
            }
        if (seg == 0) {
            #pragma unroll
            for (int bb = 0; bb < 8; bb++) {
                float4* vp = (float4*)(V1g + ((size_t)bb * 256 + o) * 4);
                *vp = make_float4(vac[bb][0], vac[bb][1], vac[bb][2], vac[bb][3]);
            }
        }
    }
}

// ---------------------------------------------------------------------------
// K4: final fused output + CP recon. block 256 = (w 128, c-sub 2).
// ---------------------------------------------------------------------------
__global__ __launch_bounds__(256) void final_kernel(
    const float* __restrict__ frm, const float* __restrict__ oth,
    const float* __restrict__ U2g, const float* __restrict__ U3g,
    const float* __restrict__ V1g, const float* __restrict__ specg,
    const float* __restrict__ rb,  const float* __restrict__ spw,
    const float* __restrict__ spb, const float* __restrict__ alphap,
    float* __restrict__ out)
{
    const int w  = threadIdx.x & 127;
    const int cc = threadIdx.x >> 7;
    const int h  = blockIdx.x;
    const int c  = blockIdx.y * 2 + cc;
    const int b  = blockIdx.z;

    const float4 u2 = *(const float4*)(U2g + ((size_t)b * 128 + w) * 4);
    const float4 u3 = *(const float4*)(U3g + ((size_t)b * 128 + h) * 4);
    const float4 v1 = *(const float4*)(V1g + ((size_t)b * 256 + c) * 4);

    const float p0 = u2.x * u3.x, p1 = u2.y * u3.y;
    const float p2 = u2.z * u3.z, p3 = u2.w * u3.w;
    const float dot = p0 + p1 + p2 + p3;
    const float att = 1.f / (1.f + expf(-(spw[0] * dot + spb[0])));
    const float cp  = v1.x * p0 + v1.y * p1 + v1.z * p2 + v1.w * p3 + rb[c];

    const float spec  = specg[b * 256 + c];
    const float Watt  = spec * att;
    const float alpha = alphap[0];

    const size_t idx = (((size_t)b * 256 + c) << 14) + ((size_t)h << 7) + w;
    const float f = frm[idx], o = oth[idx];
    out[idx]          = alpha * Watt * f + (1.f - alpha) * (1.f - Watt) * o;
    out[CP_OFF + idx] = cp;
}

// ---------------------------------------------------------------------------
extern "C" void kernel_launch(void* const* d_in, const int* in_sizes, int n_in,
                              void* d_out, int out_size, void* d_ws, size_t ws_size,
                              hipStream_t stream)
{
    const float* frm   = (const float*)d_in[0];
    const float* oth   = (const float*)d_in[1];
    const float* cw    = (const float*)d_in[2];
    const float* cb    = (const float*)d_in[3];
    const float* a1w   = (const float*)d_in[4];
    const float* a1b   = (const float*)d_in[5];
    const float* a2w   = (const float*)d_in[6];
    const float* a2b   = (const float*)d_in[7];
    const float* a3w   = (const float*)d_in[8];
    const float* a3b   = (const float*)d_in[9];
    const float* ugw   = (const float*)d_in[10];
    const float* ugb   = (const float*)d_in[11];
    const float* rw    = (const float*)d_in[12];
    const float* rb    = (const float*)d_in[13];
    const float* spw   = (const float*)d_in[14];
    const float* spb   = (const float*)d_in[15];
    const float* spaw  = (const float*)d_in[16];
    const float* spab  = (const float*)d_in[17];
    const float* spmw  = (const float*)d_in[18];
    const float* spmb  = (const float*)d_in[19];
    const float* alpha = (const float*)d_in[20];

    float* out = (float*)d_out;
    float* ws  = (float*)d_ws;

    unsigned short* Wt = (unsigned short*)out;              // 2.36 MB
    unsigned short* Xt = (unsigned short*)(out + CP_OFF);   // 134 MB in cp half
    float* U1g = out + U1G_OUT_OFF;                         // parked in d_out
    float* cf  = out + CF_OUT_OFF;

    float*    zb  = ws + ZB_OFF;
    float*    p1s = ws + P1S_OFF;
    unsigned* p1m = (unsigned*)(ws + P1M_OFF);
    float*    p2s = ws + P2S_OFF;
    unsigned* p2m = (unsigned*)(ws + P2M_OFF);
    float*    p3s = ws + P3S_OFF;
    unsigned* p3m = (unsigned*)(ws + P3M_OFF);
    float*    U2g = ws + U2_OFF;
    float*    U3g = ws + U3_OFF;
    float*    V1g = ws + V1_OFF;
    float*    spc = ws + SPEC_OFF;

    // zero zbuf + reduction partials (max keys: 0 == -inf)
    hipMemsetAsync(d_ws, 0, WS_ZERO_BYTES, stream);

    // prep: bf16 operand layouts + coefficients
    wt_kernel<<<dim3(512), 256, 0, stream>>>(cw, Wt);
    xt_kernel<<<dim3(HH, BB), 256, 0, stream>>>(frm, oth, Xt);
    coef_kernel<<<dim3(1), 256, 0, stream>>>(
        a1w, a1b, a2w, a2b, a3w, a3b, ugw, ugb, cf);

    // conv + fused reductions
    conv_mfma<<<dim3(1024), 256, 0, stream>>>(
        Wt, Xt, cb, (const unsigned short*)zb,
        p1s, p1m, p2s, p2m, p3s, p3m);

    // U1/U2/U3
    u_kernel<<<dim3(BB, 5), 256, 0, stream>>>(
        p1s, p1m, p2s, p2m, p3s, p3m, cf, U1g, U2g, U3g);

    // spec + V1
    post_kernel<<<dim3(12), 256, 0, stream>>>(
        U1g, U2g, U3g, rw, spaw, spab, spmw, spmb, V1g, spc);

    // fused output + cp (overwrites staging areas last)
    final_kernel<<<dim3(HH, CC / 2, BB), 256, 0, stream>>>(
        frm, oth, U2g, U3g, V1g, spc, rb, spw, spb, alpha, out);
}